// Round 3
// baseline (339.405 us; speedup 1.0000x reference)
//
#include <hip/hip_runtime.h>
#include <hip/hip_bf16.h>

// MMD with Gaussian kernel, sigma=1, N=M=8192, D=512.
// Off-diagonal exp(-d^2/2) underflows to 0 in fp32 (d^2 ~ 1024 +- 64), so
// bf16 MFMA dots are numerically safe; the diagonal (sole contributor) is
// masked in the epilogue and added analytically as 1/N + 1/M.
//
// R2 changes vs R1:
//  - xx/yy computed on upper-triangle tiles only (weight 2 off-diag): -33% FLOPs
//  - global_load_lds (width 16) staging with pre-swizzled SOURCE address
//    (involution col^=(row&7)<<4 on 16B slots; LDS linear; ds_read swizzled)
//  - norms + bf16-convert fused into one prep kernel (one fp32 read)

typedef __attribute__((ext_vector_type(4))) float f32x4;
typedef __attribute__((ext_vector_type(8))) short short8;

__device__ inline unsigned short f2bf_rne(float f) {
    union { float f; unsigned u; } v; v.f = f;
    return (unsigned short)((v.u + 0x7FFF + ((v.u >> 16) & 1)) >> 16);
}

__device__ inline unsigned pack_bf16_trunc(float lo, float hi) {
    union { float f; unsigned u; } a, b; a.f = lo; b.f = hi;
    return __builtin_amdgcn_perm(b.u, a.u, 0x07060302u);
}

__device__ inline void gload_lds16(const void* g, void* l) {
    __builtin_amdgcn_global_load_lds(
        (const __attribute__((address_space(1))) unsigned int*)g,
        (__attribute__((address_space(3))) unsigned int*)l,
        16, 0, 0);
}

// ---------------- fused row-norms + fp32->bf16 convert ----------------
// one wave per row (D=512: 64 lanes x 8 elems, float4 x2 in, short8 out)
__global__ void prep_kernel(const float* __restrict__ X, const float* __restrict__ Y,
                            unsigned short* __restrict__ xb, unsigned short* __restrict__ yb,
                            float* __restrict__ nx, float* __restrict__ ny,
                            int N, int M, int D) {
    int wid  = (blockIdx.x * blockDim.x + threadIdx.x) >> 6;
    int lane = threadIdx.x & 63;
    if (wid >= N + M) return;
    const float* src; unsigned short* dst; float* nrm;
    if (wid < N) { src = X + (size_t)wid * D; dst = xb + (size_t)wid * D; nrm = nx + wid; }
    else { int r = wid - N; src = Y + (size_t)r * D; dst = yb + (size_t)r * D; nrm = ny + r; }
    float s = 0.f;
    for (int k0 = lane * 8; k0 < D; k0 += 512) {
        const float4* p = (const float4*)(src + k0);
        float4 a = p[0], b = p[1];
        s += a.x*a.x + a.y*a.y + a.z*a.z + a.w*a.w;
        s += b.x*b.x + b.y*b.y + b.z*b.z + b.w*b.w;
        short8 v;
        v[0] = (short)f2bf_rne(a.x); v[1] = (short)f2bf_rne(a.y);
        v[2] = (short)f2bf_rne(a.z); v[3] = (short)f2bf_rne(a.w);
        v[4] = (short)f2bf_rne(b.x); v[5] = (short)f2bf_rne(b.y);
        v[6] = (short)f2bf_rne(b.z); v[7] = (short)f2bf_rne(b.w);
        *(short8*)(dst + k0) = v;
    }
    #pragma unroll
    for (int off = 32; off; off >>= 1) s += __shfl_down(s, off);
    if (lane == 0) *nrm = s;
}

// norms only (fallback when ws too small for bf16 buffers)
__global__ void norms_kernel(const float* __restrict__ X, const float* __restrict__ Y,
                             float* __restrict__ nx, float* __restrict__ ny,
                             int N, int M, int D) {
    int wid  = (blockIdx.x * blockDim.x + threadIdx.x) >> 6;
    int lane = threadIdx.x & 63;
    if (wid >= N + M) return;
    const float* src = (wid < N) ? (X + (size_t)wid * D) : (Y + (size_t)(wid - N) * D);
    float s = 0.f;
    for (int k = lane; k < D; k += 64) { float v = src[k]; s += v * v; }
    #pragma unroll
    for (int off = 32; off; off >>= 1) s += __shfl_down(s, off);
    if (lane == 0) { if (wid < N) nx[wid] = s; else ny[wid - N] = s; }
}

// ---------------- fused GEMM + exp + weighted reduce ----------------
// 128x128 tile, BK=64, 256 threads = 4 waves (2x2 of 64x64), 16x16x32 bf16 MFMA.
// LDS [128 rows][64 k] bf16 double-buffered. Swizzle (involution on 16B slots):
//   LDS[r][c] = global[r][c ^ ((r&7)<<4)]  (byte offsets within the 128B row)
// PRE path: global_load_lds, source address pre-swizzled, LDS dest linear.
// TRI: 1D triangular grid (bx>=by), weight x2 off-diagonal, diagonal masked.
template<bool PRE, bool TRI>
__global__ __launch_bounds__(256)
void gemm_exp_sum(const void* __restrict__ Ap, const void* __restrict__ Bp,
                  const float* __restrict__ rnorm, const float* __restrict__ cnorm,
                  float weight, float* __restrict__ out)
{
    constexpr int D = 512;
    constexpr int NK = D / 64;            // 8 K-steps
    __shared__ short lsA[2][128 * 64];    // 32 KB
    __shared__ short lsB[2][128 * 64];    // 32 KB

    const int t    = threadIdx.x;
    const int lane = t & 63, wave = t >> 6;
    const int wm   = wave >> 1, wn = wave & 1;
    const int lr   = lane & 15, lk = lane >> 4;

    int bx, by;
    if constexpr (TRI) {
        int idx = blockIdx.x;
        bx = (int)((sqrtf(8.f * (float)idx + 1.f) - 1.f) * 0.5f);
        while ((bx + 1) * (bx + 2) / 2 <= idx) ++bx;   // float-precision guard
        while (bx * (bx + 1) / 2 > idx) --bx;
        by = idx - bx * (bx + 1) / 2;                  // 0 <= by <= bx
    } else {
        bx = blockIdx.x; by = blockIdx.y;
    }
    const int tr = by * 128;
    const int tc = bx * 128;
    const float wt = TRI ? weight * ((bx == by) ? 1.0f : 2.0f) : weight;

    f32x4 acc[4][4];
    #pragma unroll
    for (int m = 0; m < 4; ++m)
        #pragma unroll
        for (int n = 0; n < 4; ++n) {
            acc[m][n][0] = 0.f; acc[m][n][1] = 0.f;
            acc[m][n][2] = 0.f; acc[m][n][3] = 0.f;
        }

    auto COMPUTE = [&](int buf) {
        #pragma unroll
        for (int ks = 0; ks < 2; ++ks) {
            short8 aF[4], bF[4];
            #pragma unroll
            for (int m = 0; m < 4; ++m) {
                int r = wm * 64 + m * 16 + lr;
                int byte = r * 128 + ((ks * 64 + lk * 16) ^ ((r & 7) << 4));
                aF[m] = *(const short8*)((const char*)(&lsA[buf][0]) + byte);
            }
            #pragma unroll
            for (int n = 0; n < 4; ++n) {
                int r = wn * 64 + n * 16 + lr;
                int byte = r * 128 + ((ks * 64 + lk * 16) ^ ((r & 7) << 4));
                bF[n] = *(const short8*)((const char*)(&lsB[buf][0]) + byte);
            }
            #pragma unroll
            for (int m = 0; m < 4; ++m)
                #pragma unroll
                for (int n = 0; n < 4; ++n)
                    acc[m][n] = __builtin_amdgcn_mfma_f32_16x16x32_bf16(aF[m], bF[n], acc[m][n], 0, 0, 0);
        }
    };

    if constexpr (PRE) {
        // ---- global_load_lds pipeline (bf16 inputs) ----
        const int l8   = lane >> 3;                    // row within 8-row group
        const int xoff = 16 * ((lane & 7) ^ l8);       // pre-swizzled source byte offset
        auto STAGE = [&](int buf, int kt) {
            #pragma unroll
            for (int i = 0; i < 4; ++i) {
                int r0 = wave * 32 + i * 8;            // wave-uniform base row
                const char* ga = (const char*)Ap + ((size_t)(tr + r0 + l8) * D + (size_t)kt * 64) * 2 + xoff;
                const char* gb = (const char*)Bp + ((size_t)(tc + r0 + l8) * D + (size_t)kt * 64) * 2 + xoff;
                gload_lds16(ga, &lsA[buf][r0 * 64]);
                gload_lds16(gb, &lsB[buf][r0 * 64]);
            }
        };
        STAGE(0, 0);
        __syncthreads();                               // prologue drain (implicit vmcnt(0))
        int cur = 0;
        for (int kt = 0; kt < NK; ++kt) {
            if (kt + 1 < NK) STAGE(cur ^ 1, kt + 1);   // prefetch other buffer
            COMPUTE(cur);
            __syncthreads();                           // drains vmcnt+lgkmcnt; next tile ready
            cur ^= 1;
        }
    } else {
        // ---- reg-staged pipeline (fp32 inputs, in-loop truncating cvt) ----
        const int srow = t >> 3;
        const int scol = (t & 7) * 8;
        float4 fa[4][2], fb[4][2];
        auto LOAD = [&](int kt) {
            #pragma unroll
            for (int i = 0; i < 4; ++i) {
                size_t ar = (size_t)(tr + i * 32 + srow) * D + kt * 64 + scol;
                size_t br = (size_t)(tc + i * 32 + srow) * D + kt * 64 + scol;
                fa[i][0] = *(const float4*)((const float*)Ap + ar);
                fa[i][1] = *(const float4*)((const float*)Ap + ar + 4);
                fb[i][0] = *(const float4*)((const float*)Bp + br);
                fb[i][1] = *(const float4*)((const float*)Bp + br + 4);
            }
        };
        auto WRITE = [&](int buf) {
            #pragma unroll
            for (int i = 0; i < 4; ++i) {
                int r = i * 32 + srow;
                int byte = r * 128 + ((scol * 2) ^ ((r & 7) << 4));
                uint4 va, vb;
                va.x = pack_bf16_trunc(fa[i][0].x, fa[i][0].y);
                va.y = pack_bf16_trunc(fa[i][0].z, fa[i][0].w);
                va.z = pack_bf16_trunc(fa[i][1].x, fa[i][1].y);
                va.w = pack_bf16_trunc(fa[i][1].z, fa[i][1].w);
                vb.x = pack_bf16_trunc(fb[i][0].x, fb[i][0].y);
                vb.y = pack_bf16_trunc(fb[i][0].z, fb[i][0].w);
                vb.z = pack_bf16_trunc(fb[i][1].x, fb[i][1].y);
                vb.w = pack_bf16_trunc(fb[i][1].z, fb[i][1].w);
                *(uint4*)((char*)(&lsA[buf][0]) + byte) = va;
                *(uint4*)((char*)(&lsB[buf][0]) + byte) = vb;
            }
        };
        LOAD(0); WRITE(0);
        int cur = 0;
        for (int kt = 0; kt < NK; ++kt) {
            __syncthreads();
            if (kt + 1 < NK) LOAD(kt + 1);
            COMPUTE(cur);
            if (kt + 1 < NK) WRITE(cur ^ 1);
            cur ^= 1;
        }
    }

    // epilogue: d^2 = rn + cn - 2*dot; exp; mask diag (TRI); weighted reduce
    float lsum = 0.f;
    const int cr0 = (lane >> 4) * 4;
    const int ccl = lane & 15;
    float cn_[4];
    #pragma unroll
    for (int n = 0; n < 4; ++n) cn_[n] = cnorm[tc + wn * 64 + n * 16 + ccl];
    float rn_[16];
    #pragma unroll
    for (int m = 0; m < 4; ++m)
        #pragma unroll
        for (int r = 0; r < 4; ++r) rn_[m * 4 + r] = rnorm[tr + wm * 64 + m * 16 + cr0 + r];

    #pragma unroll
    for (int m = 0; m < 4; ++m) {
        #pragma unroll
        for (int n = 0; n < 4; ++n) {
            #pragma unroll
            for (int r = 0; r < 4; ++r) {
                int grow = tr + wm * 64 + m * 16 + cr0 + r;
                int gcol = tc + wn * 64 + n * 16 + ccl;
                float d2 = rn_[m * 4 + r] + cn_[n] - 2.0f * acc[m][n][r];
                float v  = __expf(-0.5f * d2);
                bool skip = TRI && (grow == gcol);
                lsum += skip ? 0.f : v;
            }
        }
    }

    #pragma unroll
    for (int off = 32; off; off >>= 1) lsum += __shfl_down(lsum, off);
    __syncthreads();
    float* red = (float*)&lsA[0][0];
    if (lane == 0) red[wave] = lsum;
    __syncthreads();
    if (t == 0) atomicAdd(out, wt * (red[0] + red[1] + red[2] + red[3]));
}

__global__ void finalize_add(float* __restrict__ out, float c) {
    if (threadIdx.x == 0 && blockIdx.x == 0) out[0] += c;
}

extern "C" void kernel_launch(void* const* d_in, const int* in_sizes, int n_in,
                              void* d_out, int out_size, void* d_ws, size_t ws_size,
                              hipStream_t stream) {
    const int D = 512;
    const int N = in_sizes[0] / D;
    const int M = in_sizes[1] / D;
    const float* X = (const float*)d_in[0];
    const float* Y = (const float*)d_in[1];
    float* out = (float*)d_out;

    // ws layout: nx[N] f32 | ny[M] f32 | xb[N*D] bf16 | yb[M*D] bf16
    float* nx = (float*)d_ws;
    float* ny = nx + N;
    unsigned short* xb = (unsigned short*)(ny + M);
    unsigned short* yb = xb + (size_t)N * D;
    const size_t need = (size_t)(N + M) * 4 + (size_t)(N + M) * D * 2;
    const bool pre = ws_size >= need;   // constant across calls -> same work every call

    hipMemsetAsync(d_out, 0, sizeof(float), stream);

    const float wxx = 1.0f / ((float)N * (float)N);
    const float wyy = 1.0f / ((float)M * (float)M);
    const float wxy = -2.0f / ((float)N * (float)M);

    const int Bx = N / 128, By = M / 128;
    const int triX = Bx * (Bx + 1) / 2;
    const int triY = By * (By + 1) / 2;

    if (pre) {
        int blocks = (N + M + 3) / 4;   // 4 rows (waves) per 256-thread block
        prep_kernel<<<dim3(blocks), dim3(256), 0, stream>>>(X, Y, xb, yb, nx, ny, N, M, D);
        gemm_exp_sum<true,  true ><<<dim3(triX), dim3(256), 0, stream>>>(xb, xb, nx, nx, wxx, out);
        gemm_exp_sum<true,  true ><<<dim3(triY), dim3(256), 0, stream>>>(yb, yb, ny, ny, wyy, out);
        gemm_exp_sum<true,  false><<<dim3(M / 128, N / 128), dim3(256), 0, stream>>>(xb, yb, nx, ny, wxy, out);
    } else {
        int waves = N + M;
        norms_kernel<<<dim3((waves + 3) / 4), dim3(256), 0, stream>>>(X, Y, nx, ny, N, M, D);
        gemm_exp_sum<false, true ><<<dim3(triX), dim3(256), 0, stream>>>(X, X, nx, nx, wxx, out);
        gemm_exp_sum<false, true ><<<dim3(triY), dim3(256), 0, stream>>>(Y, Y, ny, ny, wyy, out);
        gemm_exp_sum<false, false><<<dim3(M / 128, N / 128), dim3(256), 0, stream>>>(X, Y, nx, ny, wxy, out);
    }

    // exact diagonal contribution: N/N^2 + M/M^2
    finalize_add<<<dim3(1), dim3(64), 0, stream>>>(out, 1.0f / (float)N + 1.0f / (float)M);
}

// Round 5
// 253.932 us; speedup vs baseline: 1.3366x; 1.3366x over previous
//
#include <hip/hip_runtime.h>
#include <hip/hip_bf16.h>

// MMD with Gaussian kernel, sigma=1, N=M=8192, D=512.
// Off-diagonal exp(-d^2/2) underflows to 0 in fp32 (d^2 ~ 1024 +- 64), so
// bf16 MFMA dots are numerically safe; the diagonal (sole contributor) is
// masked in the epilogue and added analytically as 1/N + 1/M.
//
// R4 = R1's reg-staged GEMM (745 TF measured; gload_lds 2-phase measured
// SLOWER at 424 TF in R3) + R3's triangle decomposition (-33% FLOPs) and
// fused prep (norms + bf16 cvt in one pass). All components HW-verified.

typedef __attribute__((ext_vector_type(4))) float f32x4;
typedef __attribute__((ext_vector_type(8))) short short8;

__device__ inline unsigned short f2bf_rne(float f) {
    union { float f; unsigned u; } v; v.f = f;
    return (unsigned short)((v.u + 0x7FFF + ((v.u >> 16) & 1)) >> 16);
}

__device__ inline unsigned pack_bf16_trunc(float lo, float hi) {
    union { float f; unsigned u; } a, b; a.f = lo; b.f = hi;
    return __builtin_amdgcn_perm(b.u, a.u, 0x07060302u);
}

// ---------------- fused row-norms + fp32->bf16 convert ----------------
// one wave per row (D=512: 64 lanes x 8 elems, float4 x2 in, short8 out)
__global__ void prep_kernel(const float* __restrict__ X, const float* __restrict__ Y,
                            unsigned short* __restrict__ xb, unsigned short* __restrict__ yb,
                            float* __restrict__ nx, float* __restrict__ ny,
                            int N, int M, int D) {
    int wid  = (blockIdx.x * blockDim.x + threadIdx.x) >> 6;
    int lane = threadIdx.x & 63;
    if (wid >= N + M) return;
    const float* src; unsigned short* dst; float* nrm;
    if (wid < N) { src = X + (size_t)wid * D; dst = xb + (size_t)wid * D; nrm = nx + wid; }
    else { int r = wid - N; src = Y + (size_t)r * D; dst = yb + (size_t)r * D; nrm = ny + r; }
    float s = 0.f;
    for (int k0 = lane * 8; k0 < D; k0 += 512) {
        const float4* p = (const float4*)(src + k0);
        float4 a = p[0], b = p[1];
        s += a.x*a.x + a.y*a.y + a.z*a.z + a.w*a.w;
        s += b.x*b.x + b.y*b.y + b.z*b.z + b.w*b.w;
        short8 v;
        v[0] = (short)f2bf_rne(a.x); v[1] = (short)f2bf_rne(a.y);
        v[2] = (short)f2bf_rne(a.z); v[3] = (short)f2bf_rne(a.w);
        v[4] = (short)f2bf_rne(b.x); v[5] = (short)f2bf_rne(b.y);
        v[6] = (short)f2bf_rne(b.z); v[7] = (short)f2bf_rne(b.w);
        *(short8*)(dst + k0) = v;
    }
    #pragma unroll
    for (int off = 32; off; off >>= 1) s += __shfl_down(s, off);
    if (lane == 0) *nrm = s;
}

// norms only (fallback when ws too small for bf16 buffers)
__global__ void norms_kernel(const float* __restrict__ X, const float* __restrict__ Y,
                             float* __restrict__ nx, float* __restrict__ ny,
                             int N, int M, int D) {
    int wid  = (blockIdx.x * blockDim.x + threadIdx.x) >> 6;
    int lane = threadIdx.x & 63;
    if (wid >= N + M) return;
    const float* src = (wid < N) ? (X + (size_t)wid * D) : (Y + (size_t)(wid - N) * D);
    float s = 0.f;
    for (int k = lane; k < D; k += 64) { float v = src[k]; s += v * v; }
    #pragma unroll
    for (int off = 32; off; off >>= 1) s += __shfl_down(s, off);
    if (lane == 0) { if (wid < N) nx[wid] = s; else ny[wid - N] = s; }
}

// ---------------- fused GEMM + exp + weighted reduce ----------------
// 128x128 tile, BK=64, 256 threads = 4 waves (2x2 of 64x64), 16x16x32 bf16 MFMA.
// LDS [128 rows][64 k] bf16 double-buffered, reg-staged (global->reg->ds_write),
// XOR-swizzled on 16B slots: byte = r*128 + (col16B ^ ((r&7)<<4)) -> conflict-free.
// PRE: inputs are pre-converted bf16; else fp32 with in-loop v_perm truncation.
// TRI: 1D triangular grid (bx>=by), weight x2 off-diagonal, diagonal masked.
template<bool PRE, bool TRI>
__global__ __launch_bounds__(256)
void gemm_exp_sum(const void* __restrict__ Ap, const void* __restrict__ Bp,
                  const float* __restrict__ rnorm, const float* __restrict__ cnorm,
                  float weight, float* __restrict__ out)
{
    constexpr int D = 512;
    constexpr int NK = D / 64;            // 8 K-steps
    __shared__ short lsA[2][128 * 64];    // 32 KB
    __shared__ short lsB[2][128 * 64];    // 32 KB

    const int t    = threadIdx.x;
    const int lane = t & 63, wave = t >> 6;
    const int wm   = wave >> 1, wn = wave & 1;
    const int lr   = lane & 15, lk = lane >> 4;

    int bx, by;
    if constexpr (TRI) {
        int idx = blockIdx.x;
        bx = (int)((sqrtf(8.f * (float)idx + 1.f) - 1.f) * 0.5f);
        while ((bx + 1) * (bx + 2) / 2 <= idx) ++bx;   // float-precision guard
        while (bx * (bx + 1) / 2 > idx) --bx;
        by = idx - bx * (bx + 1) / 2;                  // 0 <= by <= bx
    } else {
        bx = blockIdx.x; by = blockIdx.y;
    }
    const int tr = by * 128;
    const int tc = bx * 128;
    const float wt = TRI ? weight * ((bx == by) ? 1.0f : 2.0f) : weight;

    const int srow = t >> 3;              // 0..31 (row within 32-row stripe)
    const int scol = (t & 7) * 8;         // k offset (elements), 16B per thread

    uint4  sa[4], sb[4];
    float4 fa[4][2], fb[4][2];

    f32x4 acc[4][4];
    #pragma unroll
    for (int m = 0; m < 4; ++m)
        #pragma unroll
        for (int n = 0; n < 4; ++n) {
            acc[m][n][0] = 0.f; acc[m][n][1] = 0.f;
            acc[m][n][2] = 0.f; acc[m][n][3] = 0.f;
        }

    auto LOAD = [&](int kt) {
        #pragma unroll
        for (int i = 0; i < 4; ++i) {
            size_t ar = (size_t)(tr + i * 32 + srow) * D + kt * 64 + scol;
            size_t br = (size_t)(tc + i * 32 + srow) * D + kt * 64 + scol;
            if constexpr (PRE) {
                sa[i] = *(const uint4*)((const unsigned short*)Ap + ar);
                sb[i] = *(const uint4*)((const unsigned short*)Bp + br);
            } else {
                fa[i][0] = *(const float4*)((const float*)Ap + ar);
                fa[i][1] = *(const float4*)((const float*)Ap + ar + 4);
                fb[i][0] = *(const float4*)((const float*)Bp + br);
                fb[i][1] = *(const float4*)((const float*)Bp + br + 4);
            }
        }
    };

    auto WRITE = [&](int buf) {
        #pragma unroll
        for (int i = 0; i < 4; ++i) {
            int r = i * 32 + srow;
            int byte = r * 128 + ((scol * 2) ^ ((r & 7) << 4));
            uint4 va, vb;
            if constexpr (PRE) { va = sa[i]; vb = sb[i]; }
            else {
                va.x = pack_bf16_trunc(fa[i][0].x, fa[i][0].y);
                va.y = pack_bf16_trunc(fa[i][0].z, fa[i][0].w);
                va.z = pack_bf16_trunc(fa[i][1].x, fa[i][1].y);
                va.w = pack_bf16_trunc(fa[i][1].z, fa[i][1].w);
                vb.x = pack_bf16_trunc(fb[i][0].x, fb[i][0].y);
                vb.y = pack_bf16_trunc(fb[i][0].z, fb[i][0].w);
                vb.z = pack_bf16_trunc(fb[i][1].x, fb[i][1].y);
                vb.w = pack_bf16_trunc(fb[i][1].z, fb[i][1].w);
            }
            *(uint4*)((char*)(&lsA[buf][0]) + byte) = va;
            *(uint4*)((char*)(&lsB[buf][0]) + byte) = vb;
        }
    };

    auto COMPUTE = [&](int buf) {
        #pragma unroll
        for (int ks = 0; ks < 2; ++ks) {
            short8 aF[4], bF[4];
            #pragma unroll
            for (int m = 0; m < 4; ++m) {
                int r = wm * 64 + m * 16 + lr;
                int byte = r * 128 + ((ks * 64 + lk * 16) ^ ((r & 7) << 4));
                aF[m] = *(const short8*)((const char*)(&lsA[buf][0]) + byte);
            }
            #pragma unroll
            for (int n = 0; n < 4; ++n) {
                int r = wn * 64 + n * 16 + lr;
                int byte = r * 128 + ((ks * 64 + lk * 16) ^ ((r & 7) << 4));
                bF[n] = *(const short8*)((const char*)(&lsB[buf][0]) + byte);
            }
            #pragma unroll
            for (int m = 0; m < 4; ++m)
                #pragma unroll
                for (int n = 0; n < 4; ++n)
                    acc[m][n] = __builtin_amdgcn_mfma_f32_16x16x32_bf16(aF[m], bF[n], acc[m][n], 0, 0, 0);
        }
    };

    // pipeline: stage tile 0, then {barrier; issue next loads; compute; write next}
    LOAD(0); WRITE(0);
    int cur = 0;
    for (int kt = 0; kt < NK; ++kt) {
        __syncthreads();
        if (kt + 1 < NK) LOAD(kt + 1);
        COMPUTE(cur);
        if (kt + 1 < NK) WRITE(cur ^ 1);
        cur ^= 1;
    }

    // epilogue: d^2 = rn + cn - 2*dot; exp; mask diag (TRI); weighted reduce
    float lsum = 0.f;
    const int cr0 = (lane >> 4) * 4;
    const int ccl = lane & 15;
    float cn_[4];
    #pragma unroll
    for (int n = 0; n < 4; ++n) cn_[n] = cnorm[tc + wn * 64 + n * 16 + ccl];
    float rn_[16];
    #pragma unroll
    for (int m = 0; m < 4; ++m)
        #pragma unroll
        for (int r = 0; r < 4; ++r) rn_[m * 4 + r] = rnorm[tr + wm * 64 + m * 16 + cr0 + r];

    #pragma unroll
    for (int m = 0; m < 4; ++m) {
        #pragma unroll
        for (int n = 0; n < 4; ++n) {
            #pragma unroll
            for (int r = 0; r < 4; ++r) {
                int grow = tr + wm * 64 + m * 16 + cr0 + r;
                int gcol = tc + wn * 64 + n * 16 + ccl;
                float d2 = rn_[m * 4 + r] + cn_[n] - 2.0f * acc[m][n][r];
                float v  = __expf(-0.5f * d2);
                bool skip = TRI && (grow == gcol);
                lsum += skip ? 0.f : v;
            }
        }
    }

    #pragma unroll
    for (int off = 32; off; off >>= 1) lsum += __shfl_down(lsum, off);
    __syncthreads();
    float* red = (float*)&lsA[0][0];
    if (lane == 0) red[wave] = lsum;
    __syncthreads();
    if (t == 0) atomicAdd(out, wt * (red[0] + red[1] + red[2] + red[3]));
}

__global__ void finalize_add(float* __restrict__ out, float c) {
    if (threadIdx.x == 0 && blockIdx.x == 0) out[0] += c;
}

extern "C" void kernel_launch(void* const* d_in, const int* in_sizes, int n_in,
                              void* d_out, int out_size, void* d_ws, size_t ws_size,
                              hipStream_t stream) {
    const int D = 512;
    const int N = in_sizes[0] / D;
    const int M = in_sizes[1] / D;
    const float* X = (const float*)d_in[0];
    const float* Y = (const float*)d_in[1];
    float* out = (float*)d_out;

    // ws layout: nx[N] f32 | ny[M] f32 | xb[N*D] bf16 | yb[M*D] bf16
    float* nx = (float*)d_ws;
    float* ny = nx + N;
    unsigned short* xb = (unsigned short*)(ny + M);
    unsigned short* yb = xb + (size_t)N * D;
    const size_t need = (size_t)(N + M) * 4 + (size_t)(N + M) * D * 2;
    const bool pre = ws_size >= need;   // constant across calls -> same work every call

    hipMemsetAsync(d_out, 0, sizeof(float), stream);

    const float wxx = 1.0f / ((float)N * (float)N);
    const float wyy = 1.0f / ((float)M * (float)M);
    const float wxy = -2.0f / ((float)N * (float)M);

    const int Bx = N / 128, By = M / 128;
    const int triX = Bx * (Bx + 1) / 2;
    const int triY = By * (By + 1) / 2;

    if (pre) {
        int blocks = (N + M + 3) / 4;   // 4 rows (waves) per 256-thread block
        prep_kernel<<<dim3(blocks), dim3(256), 0, stream>>>(X, Y, xb, yb, nx, ny, N, M, D);
        gemm_exp_sum<true,  true ><<<dim3(triX), dim3(256), 0, stream>>>(xb, xb, nx, nx, wxx, out);
        gemm_exp_sum<true,  true ><<<dim3(triY), dim3(256), 0, stream>>>(yb, yb, ny, ny, wyy, out);
        gemm_exp_sum<true,  false><<<dim3(M / 128, N / 128), dim3(256), 0, stream>>>(xb, yb, nx, ny, wxy, out);
    } else {
        int waves = N + M;
        norms_kernel<<<dim3((waves + 3) / 4), dim3(256), 0, stream>>>(X, Y, nx, ny, N, M, D);
        gemm_exp_sum<false, true ><<<dim3(triX), dim3(256), 0, stream>>>(X, X, nx, nx, wxx, out);
        gemm_exp_sum<false, true ><<<dim3(triY), dim3(256), 0, stream>>>(Y, Y, ny, ny, wyy, out);
        gemm_exp_sum<false, false><<<dim3(M / 128, N / 128), dim3(256), 0, stream>>>(X, Y, nx, ny, wxy, out);
    }

    // exact diagonal contribution: N/N^2 + M/M^2
    finalize_add<<<dim3(1), dim3(64), 0, stream>>>(out, 1.0f / (float)N + 1.0f / (float)M);
}